// Round 4
// baseline (2500.285 us; speedup 1.0000x reference)
//
#include <hip/hip_runtime.h>

// Residual VQ: x [B,N,D] fp32, codebooks [Q,C,D] fp32
// Outputs (flat fp32 in d_out): qout [B*N*D], indices [B*N*Q] (as float), losses [Q]
constexpr int Bq = 8;
constexpr int Nn = 4096;
constexpr int Dd = 256;
constexpr int Qq = 8;
constexpr int Cc = 1024;
constexpr int Mm = Bq * Nn;      // 32768 tokens
constexpr int TT = 16;           // tokens per block
constexpr int NT = 256;          // threads per block

// ---------------------------------------------------------------------------
// prep: cnorm[q*C+c] = sum_d cb[q][c][d]^2 ; zero loss accumulators
__global__ void prep_kernel(const float* __restrict__ cbs,
                            float* __restrict__ cnorm,
                            float* __restrict__ loss_acc) {
  const int wave = threadIdx.x >> 6;
  const int lane = threadIdx.x & 63;
  const int row  = blockIdx.x * 4 + wave;            // 0 .. Q*C-1
  const float4* r4 = reinterpret_cast<const float4*>(cbs + (size_t)row * Dd);
  const float4 v = r4[lane];                          // 64 lanes x float4 = 256
  float s = v.x * v.x + v.y * v.y + v.z * v.z + v.w * v.w;
#pragma unroll
  for (int off = 32; off; off >>= 1) s += __shfl_down(s, off);
  if (lane == 0) cnorm[row] = s;
  if (blockIdx.x == 0 && threadIdx.x < Qq) loss_acc[threadIdx.x] = 0.0f;
}

// ---------------------------------------------------------------------------
// transpose codebooks: cbT[q][d4][c] = float4(cb[q][c][4*d4 .. 4*d4+3])
constexpr int TC = 64;   // codewords per block
constexpr int TD = 16;   // d4 chunk
__global__ __launch_bounds__(NT)
void transpose_cb(const float* __restrict__ cbs, float4* __restrict__ cbT) {
  __shared__ float4 tile[TC][TD + 1];
  const int q  = blockIdx.x / (Cc / TC);
  const int c0 = (blockIdx.x % (Cc / TC)) * TC;
  const float4* src = reinterpret_cast<const float4*>(cbs + ((size_t)q * Cc + c0) * Dd);
  const int tid = threadIdx.x;
#pragma unroll 1
  for (int d40 = 0; d40 < Dd / 4; d40 += TD) {
#pragma unroll
    for (int it = 0; it < (TC * TD) / NT; ++it) {
      const int j = it * NT + tid;
      const int row = j / TD, col = j % TD;
      tile[row][col] = src[(size_t)row * (Dd / 4) + d40 + col];
    }
    __syncthreads();
#pragma unroll
    for (int it = 0; it < (TC * TD) / NT; ++it) {
      const int j = it * NT + tid;
      const int dd = j / TC, cc = j % TC;
      cbT[((size_t)q * (Dd / 4) + d40 + dd) * Cc + c0 + cc] = tile[cc][dd];
    }
    __syncthreads();
  }
}

// ---------------------------------------------------------------------------
// one VQ stage, fully fused: distances + argmin + gather + residual/qout/loss
// grid: Mm/TT blocks of NT threads.  Two codeword passes of 2 codewords/thread
// keep per-thread live state ~96 VGPRs (acc 32 + min 32 + dbuf 16 + misc) so
// the compiler never round-trips accumulators through AGPRs.
__global__ __launch_bounds__(NT, 4)
void vq_stage(const float* __restrict__ cb,      // [C][D] this stage (row layout, epilogue gather)
              const float4* __restrict__ cbt,    // [D/4][C] this stage (transposed, streaming)
              const float* __restrict__ cnorm,   // [C]   this stage
              const float* __restrict__ rin,     // [M][D] residual in
              float* __restrict__ rout,          // [M][D] residual out
              float* __restrict__ qout,          // [M][D] accumulated quantized
              float* __restrict__ idx_out,       // [M][Q] indices as float
              float* __restrict__ loss_acc,      // [Q] loss sums
              int q) {
  __shared__ float4 rs[TT][Dd / 4];               // 16 KB residual tile
  __shared__ float red_v[4][TT];
  __shared__ int   red_i[4][TT];
  __shared__ int   win[TT];

  const int tid  = threadIdx.x;
  const int tok0 = blockIdx.x * TT;

  // stage residual tile: TT*D floats = 1024 float4; 4 per thread, coalesced
  {
    const float4* src = reinterpret_cast<const float4*>(rin + (size_t)tok0 * Dd);
    float4* dst = &rs[0][0];
#pragma unroll
    for (int k = 0; k < (TT * Dd / 4) / NT; ++k) dst[tid + k * NT] = src[tid + k * NT];
  }
  __syncthreads();

  float minv[TT];
  int   mini[TT];
#pragma unroll
  for (int m = 0; m < TT; ++m) { minv[m] = 3.4e38f; mini[m] = 0; }

  // per-thread candidates ascending: pass0 {tid, tid+256}, pass1 {tid+512, tid+768}
#pragma unroll 1
  for (int pass = 0; pass < 2; ++pass) {
    const int c0 = pass * 512 + tid;
    const int c1 = c0 + 256;
    float acc0[TT], acc1[TT];
#pragma unroll
    for (int m = 0; m < TT; ++m) { acc0[m] = 0.0f; acc1[m] = 0.0f; }

    float4 a0 = cbt[c0];
    float4 a1 = cbt[c1];
#pragma unroll 1
    for (int d4 = 0; d4 < Dd / 4; d4 += 2) {
      const float4* p1 = cbt + (size_t)(d4 + 1) * Cc;
      float4 b0 = p1[c0];
      float4 b1 = p1[c1];
#pragma unroll
      for (int m = 0; m < TT; ++m) {
        const float4 r = rs[m][d4];                     // LDS broadcast
        acc0[m] += r.x * a0.x; acc0[m] += r.y * a0.y;
        acc0[m] += r.z * a0.z; acc0[m] += r.w * a0.w;
        acc1[m] += r.x * a1.x; acc1[m] += r.y * a1.y;
        acc1[m] += r.z * a1.z; acc1[m] += r.w * a1.w;
      }
      if (d4 + 2 < Dd / 4) {
        const float4* p2 = cbt + (size_t)(d4 + 2) * Cc;
        a0 = p2[c0];
        a1 = p2[c1];
      }
#pragma unroll
      for (int m = 0; m < TT; ++m) {
        const float4 r = rs[m][d4 + 1];
        acc0[m] += r.x * b0.x; acc0[m] += r.y * b0.y;
        acc0[m] += r.z * b0.z; acc0[m] += r.w * b0.w;
        acc1[m] += r.x * b1.x; acc1[m] += r.y * b1.y;
        acc1[m] += r.z * b1.z; acc1[m] += r.w * b1.w;
      }
    }
    // NOTE: per-(token,codeword) FMA chain: ascending d4, components x,y,z,w,
    // from 0.0f — bitwise-identical to the validated round-1/2/3 kernels.
    const float cn0 = cnorm[c0];
    const float cn1 = cnorm[c1];
#pragma unroll
    for (int m = 0; m < TT; ++m) {
      const float s0 = cn0 - 2.0f * acc0[m];
      if (s0 < minv[m]) { minv[m] = s0; mini[m] = c0; }
      const float s1 = cn1 - 2.0f * acc1[m];
      if (s1 < minv[m]) { minv[m] = s1; mini[m] = c1; }
    }
  }

  // wave argmin reduce (value, then lowest index on exact ties)
#pragma unroll
  for (int m = 0; m < TT; ++m) {
    float v = minv[m];
    int   i = mini[m];
#pragma unroll
    for (int s = 32; s; s >>= 1) {
      const float ov = __shfl_xor(v, s);
      const int   oi = __shfl_xor(i, s);
      if (ov < v || (ov == v && oi < i)) { v = ov; i = oi; }
    }
    minv[m] = v;
    mini[m] = i;
  }
  const int lane = tid & 63;
  const int wv   = tid >> 6;
  if (lane == 0) {
#pragma unroll
    for (int m = 0; m < TT; ++m) { red_v[wv][m] = minv[m]; red_i[wv][m] = mini[m]; }
  }
  __syncthreads();
  if (tid < TT) {
    float v = red_v[0][tid];
    int   i = red_i[0][tid];
#pragma unroll
    for (int w = 1; w < 4; ++w) {
      const float ov = red_v[w][tid];
      const int   oi = red_i[w][tid];
      if (ov < v || (ov == v && oi < i)) { v = ov; i = oi; }
    }
    win[tid] = i;
    idx_out[(size_t)(tok0 + tid) * Qq + q] = (float)i;   // indices as float
  }
  __syncthreads();

  // epilogue: gather winner codeword, loss, residual & qout update.
  //   e = q - r; q_st = r + e; r_new = r - q_st; qout += q_st; loss += e^2
  float lsum = 0.0f;
  {
    const float4* cb4   = reinterpret_cast<const float4*>(cb);
    float4* routp = reinterpret_cast<float4*>(rout + (size_t)tok0 * Dd);
    float4* qoutp = reinterpret_cast<float4*>(qout + (size_t)tok0 * Dd);
#pragma unroll
    for (int k = 0; k < (TT * Dd / 4) / NT; ++k) {
      const int j  = tid + k * NT;
      const int m  = j >> 6;        // wave-uniform token
      const int d4 = j & 63;
      const int widx = win[m];
      const float4 cv = cb4[(size_t)widx * (Dd / 4) + d4];
      const float4 rv = rs[m][d4];
      const float ex = cv.x - rv.x, ey = cv.y - rv.y, ez = cv.z - rv.z, ew = cv.w - rv.w;
      const float qsx = rv.x + ex, qsy = rv.y + ey, qsz = rv.z + ez, qsw = rv.w + ew;
      lsum += ex * ex + ey * ey + ez * ez + ew * ew;
      routp[j] = make_float4(rv.x - qsx, rv.y - qsy, rv.z - qsz, rv.w - qsw);
      float4 qo;
      if (q == 0) {
        qo = make_float4(qsx, qsy, qsz, qsw);            // overwrite (no stale state)
      } else {
        const float4 old = qoutp[j];
        qo = make_float4(old.x + qsx, old.y + qsy, old.z + qsz, old.w + qsw);
      }
      qoutp[j] = qo;
    }
  }
#pragma unroll
  for (int s = 32; s; s >>= 1) lsum += __shfl_xor(lsum, s);
  if (lane == 0) atomicAdd(&loss_acc[q], lsum);
}

// ---------------------------------------------------------------------------
__global__ void finalize_losses(const float* __restrict__ loss_acc,
                                float* __restrict__ loss_out) {
  if (threadIdx.x < Qq) loss_out[threadIdx.x] = loss_acc[threadIdx.x] * (1.0f / (float)(Mm * Dd));
}

extern "C" void kernel_launch(void* const* d_in, const int* in_sizes, int n_in,
                              void* d_out, int out_size, void* d_ws, size_t ws_size,
                              hipStream_t stream) {
  const float* x   = (const float*)d_in[0];   // [B,N,D]
  const float* cbs = (const float*)d_in[1];   // [Q,C,D]
  float* out      = (float*)d_out;
  float* qout     = out;                               // M*D
  float* idx_out  = out + (size_t)Mm * Dd;             // M*Q
  float* loss_out = idx_out + (size_t)Mm * Qq;         // Q

  float* residual = (float*)d_ws;                      // M*D floats = 32 MB
  float* loss_acc = residual + (size_t)Mm * Dd;        // 64 floats
  float* cnorm    = loss_acc + 64;                     // Q*C floats
  float4* cbT     = reinterpret_cast<float4*>(cnorm + (size_t)Qq * Cc);  // Q*(D/4)*C float4 = 8 MB

  prep_kernel<<<(Qq * Cc) / 4, NT, 0, stream>>>(cbs, cnorm, loss_acc);
  transpose_cb<<<Qq * (Cc / TC), NT, 0, stream>>>(cbs, cbT);

  for (int q = 0; q < Qq; ++q) {
    const float* rin = (q == 0) ? x : residual;
    vq_stage<<<Mm / TT, NT, 0, stream>>>(cbs + (size_t)q * Cc * Dd,
                                         cbT + (size_t)q * (Dd / 4) * Cc,
                                         cnorm + (size_t)q * Cc,
                                         rin, residual,
                                         qout, idx_out, loss_acc, q);
  }

  finalize_losses<<<1, 64, 0, stream>>>(loss_acc, loss_out);
}

// Round 5
// 1871.134 us; speedup vs baseline: 1.3362x; 1.3362x over previous
//
#include <hip/hip_runtime.h>

// Residual VQ via bf16-split MFMA distances + exact-fp32-chain margin rescue.
// x [B,N,D] fp32, codebooks [Q,C,D] fp32.
// d_out (flat fp32): qout [M*D], indices [M*Q] (as float), losses [Q]
typedef __attribute__((ext_vector_type(8))) short short8;
typedef __attribute__((ext_vector_type(4))) float f32x4;

constexpr int Bq = 8, Nn = 4096, Dd = 256, Qq = 8, Cc = 1024;
constexpr int Mm = Bq * Nn;        // 32768 tokens
constexpr int TOK = 64;            // tokens per block (4 waves x 16)
constexpr int NT = 256;
constexpr int LCAP = 16;           // rescue list capacity per token
constexpr float MARGIN = 0.5f;     // >= 2*eps(|mfma-approx - fp32-chain| on scores)

__device__ inline unsigned short f2bf(float f) {          // fp32 -> bf16 RNE
  unsigned u = __float_as_uint(f);
  unsigned r = (u + 0x7FFFu + ((u >> 16) & 1u)) >> 16;
  return (unsigned short)r;
}
__device__ inline float bf2f(unsigned short h) { return __uint_as_float(((unsigned)h) << 16); }

// ---------------------------------------------------------------------------
// prep: cnorm[q*C+c] = sum_d cb[q][c][d]^2 ; zero loss accumulators
__global__ void prep_kernel(const float* __restrict__ cbs,
                            float* __restrict__ cnorm,
                            float* __restrict__ loss_acc) {
  const int wave = threadIdx.x >> 6;
  const int lane = threadIdx.x & 63;
  const int row  = blockIdx.x * 4 + wave;            // 0 .. Q*C-1
  const float4* r4 = reinterpret_cast<const float4*>(cbs + (size_t)row * Dd);
  const float4 v = r4[lane];
  float s = v.x * v.x + v.y * v.y + v.z * v.z + v.w * v.w;
#pragma unroll
  for (int off = 32; off; off >>= 1) s += __shfl_down(s, off);
  if (lane == 0) cnorm[row] = s;
  if (blockIdx.x == 0 && threadIdx.x < Qq) loss_acc[threadIdx.x] = 0.0f;
}

// ---------------------------------------------------------------------------
// Build frag-major bf16 hi/lo codebook: Bfrag[q][nt][ks][lane] (short8 each) =
// cb[q][ nt*16 + (lane&15) ][ ks*32 + (lane>>4)*8 + j ], j=0..7.
// One 16B load per lane in the GEMM, lane-contiguous (perfectly coalesced).
__global__ __launch_bounds__(NT)
void build_bfrag(const float* __restrict__ cbs,
                 short* __restrict__ Bh, short* __restrict__ Bl) {
  const int q    = blockIdx.x >> 6;      // grid = Q*64
  const int nt   = blockIdx.x & 63;
  const int lane = threadIdx.x & 63;
  const int ks0  = threadIdx.x >> 6;     // 0..3
#pragma unroll
  for (int h = 0; h < 2; ++h) {
    const int ks = ks0 + h * 4;
    const int c  = nt * 16 + (lane & 15);
    const int k  = ks * 32 + (lane >> 4) * 8;
    const float* src = cbs + ((size_t)(q * Cc + c)) * Dd + k;
    short8 hi, lo;
#pragma unroll
    for (int j = 0; j < 8; ++j) {
      const float f = src[j];
      const unsigned short hb = f2bf(f);
      hi[j] = (short)hb;
      lo[j] = (short)f2bf(f - bf2f(hb));
    }
    const size_t off = (((size_t)(q * 64 + nt) * 8 + ks) * 64 + lane);
    ((short8*)Bh)[off] = hi;
    ((short8*)Bl)[off] = lo;
  }
}

// ---------------------------------------------------------------------------
// exact fp32-chain score (bitwise-identical to the validated rounds-1..4 chain)
__device__ float exact_score(const float4* tile, int t, int sw,
                             const float* cb, const float* cnorm, int cand) {
  const float4* cv = reinterpret_cast<const float4*>(cb + (size_t)cand * Dd);
  float a = 0.0f;
#pragma unroll 1
  for (int d4 = 0; d4 < 64; ++d4) {
    const float4 rv = tile[(t * 64 + d4) ^ sw];
    const float4 c4 = cv[d4];
    a += rv.x * c4.x; a += rv.y * c4.y; a += rv.z * c4.z; a += rv.w * c4.w;
  }
  return cnorm[cand] - 2.0f * a;
}

// ---------------------------------------------------------------------------
// one VQ stage: bf16-split MFMA scores + margin collection -> rescue -> epilogue
// grid: Mm/TOK = 512 blocks x 256 threads (4 waves; wave w owns tokens w*16..+16)
__global__ __launch_bounds__(NT)
void vq_stage(const float* __restrict__ cb,      // [C][D] fp32 this stage
              const short8* __restrict__ bh,     // frag-major bf16 hi, this stage
              const short8* __restrict__ bl,     // frag-major bf16 lo
              const float* __restrict__ cnorm,   // [C] this stage
              const float* __restrict__ rin,     // [M][D] residual in
              float* __restrict__ rout,          // [M][D] residual out
              float* __restrict__ qout,          // [M][D] accumulated quantized
              float* __restrict__ idx_out,       // [M][Q] indices as float
              float* __restrict__ loss_acc,      // [Q]
              int q) {
  __shared__ float4 tile[TOK * 64];              // 64 KB fp32 residual, idx ^ (tok&7) swizzle
  __shared__ int cnt[TOK];
  __shared__ int list[TOK][LCAP];
  __shared__ int win[TOK];

  const int tid  = threadIdx.x;
  const int lane = tid & 63;
  const int wv   = tid >> 6;
  const int tok0 = blockIdx.x * TOK;

  // ---- phase A: stage fp32 residual tile (coalesced, XOR-swizzled rows)
  {
    const float4* src = reinterpret_cast<const float4*>(rin + (size_t)tok0 * Dd);
#pragma unroll
    for (int k = 0; k < 16; ++k) {
      const int j = tid + k * NT;
      const int tk = j >> 6, d4 = j & 63;
      tile[(tk * 64 + d4) ^ (tk & 7)] = src[j];
    }
  }
  if (tid < TOK) cnt[tid] = 0;
  __syncthreads();

  // ---- phase A2: per-lane A-fragments in registers (bf16 hi/lo)
  // lane holds token wv*16 + (lane&15); k-chunk (lane>>4)*8 within each ks*32
  short8 ah[8], al[8];
  {
    const int tk = wv * 16 + (lane & 15);
    const int sw = tk & 7;
#pragma unroll
    for (int ks = 0; ks < 8; ++ks) {
      const int d4 = ks * 8 + (lane >> 4) * 2;
      const float4 f0 = tile[(tk * 64 + d4) ^ sw];
      const float4 f1 = tile[(tk * 64 + d4 + 1) ^ sw];
      const float v[8] = {f0.x, f0.y, f0.z, f0.w, f1.x, f1.y, f1.z, f1.w};
#pragma unroll
      for (int j = 0; j < 8; ++j) {
        const unsigned short hb = f2bf(v[j]);
        ah[ks][j] = (short)hb;
        al[ks][j] = (short)f2bf(v[j] - bf2f(hb));
      }
    }
  }

  // ---- phase B: 64 N-tiles of 16 candidates, processed in pairs for MFMA ILP
  float runm[4] = {3.4e38f, 3.4e38f, 3.4e38f, 3.4e38f};
  const int col = lane & 15;
  const int g   = lane >> 4;                     // token rows g*4 .. g*4+3
#pragma unroll 1
  for (int np = 0; np < 32; ++np) {
    const int nt0 = np * 2;
    const float cnA = cnorm[nt0 * 16 + col];
    const float cnB = cnorm[nt0 * 16 + 16 + col];
    f32x4 accA = {0.f, 0.f, 0.f, 0.f};
    f32x4 accB = {0.f, 0.f, 0.f, 0.f};
    const short8* bphA = bh + ((size_t)nt0 * 8) * 64 + lane;
    const short8* bplA = bl + ((size_t)nt0 * 8) * 64 + lane;
#pragma unroll
    for (int ks = 0; ks < 8; ++ks) {
      const short8 vbhA = bphA[ks * 64];
      const short8 vblA = bplA[ks * 64];
      const short8 vbhB = bphA[(8 + ks) * 64];
      const short8 vblB = bplA[(8 + ks) * 64];
      accA = __builtin_amdgcn_mfma_f32_16x16x32_bf16(ah[ks], vbhA, accA, 0, 0, 0);
      accB = __builtin_amdgcn_mfma_f32_16x16x32_bf16(ah[ks], vbhB, accB, 0, 0, 0);
      accA = __builtin_amdgcn_mfma_f32_16x16x32_bf16(ah[ks], vblA, accA, 0, 0, 0);
      accB = __builtin_amdgcn_mfma_f32_16x16x32_bf16(ah[ks], vblB, accB, 0, 0, 0);
      accA = __builtin_amdgcn_mfma_f32_16x16x32_bf16(al[ks], vbhA, accA, 0, 0, 0);
      accB = __builtin_amdgcn_mfma_f32_16x16x32_bf16(al[ks], vbhB, accB, 0, 0, 0);
    }
    // sequential bookkeeping per N-tile (ascending cand order preserved)
#pragma unroll
    for (int half = 0; half < 2; ++half) {
      const f32x4 acc = half ? accB : accA;
      const float cn  = half ? cnB : cnA;
      const int cbase = (nt0 + half) * 16 + col;
      float s[4];
#pragma unroll
      for (int r = 0; r < 4; ++r) s[r] = cn - 2.0f * acc[r];
#pragma unroll
      for (int r = 0; r < 4; ++r) {
        float v = s[r];
#pragma unroll
        for (int m = 1; m < 16; m <<= 1) {
          const float o = __shfl_xor(v, m);
          v = o < v ? o : v;
        }
        const float nr = v < runm[r] ? v : runm[r];
        runm[r] = nr;
        if (s[r] <= nr + MARGIN) {
          const int t = wv * 16 + g * 4 + r;
          const int pos = atomicAdd(&cnt[t], 1);
          if (pos < LCAP) list[t][pos] = cbase;
        }
      }
    }
  }
  __syncthreads();

  // ---- phase C: rescue (one thread per token). cnt==1 -> proven exact winner.
  if (tid < TOK) {
    const int t = tid;
    const int sw = t & 7;
    const int c_ = cnt[t];
    int wdx;
    if (c_ == 1) {
      wdx = list[t][0];
    } else if (c_ <= LCAP) {
      float best = 3.4e38f; wdx = 1 << 30;
      for (int it = 0; it < c_; ++it) {
        const int cand = list[t][it];
        const float sc = exact_score(tile, t, sw, cb, cnorm, cand);
        if (sc < best || (sc == best && cand < wdx)) { best = sc; wdx = cand; }
      }
    } else {            // overflow safety net: full exact scan (never expected)
      float best = 3.4e38f; wdx = 1 << 30;
      for (int cand = 0; cand < Cc; ++cand) {
        const float sc = exact_score(tile, t, sw, cb, cnorm, cand);
        if (sc < best) { best = sc; wdx = cand; }
      }
    }
    win[t] = wdx;
    idx_out[(size_t)(tok0 + t) * Qq + q] = (float)wdx;
  }
  __syncthreads();

  // ---- phase D: epilogue (bitwise-validated elementwise sequence)
  //   e = q - r; q_st = r + e; r_new = r - q_st; qout += q_st; loss += e^2
  float lsum = 0.0f;
  {
    const float4* cb4 = reinterpret_cast<const float4*>(cb);
    float4* routp = reinterpret_cast<float4*>(rout + (size_t)tok0 * Dd);
    float4* qoutp = reinterpret_cast<float4*>(qout + (size_t)tok0 * Dd);
#pragma unroll
    for (int k = 0; k < 16; ++k) {
      const int j = tid + k * NT;
      const int tk = j >> 6, d4 = j & 63;
      const int widx = win[tk];
      const float4 cv = cb4[(size_t)widx * 64 + d4];
      const float4 rv = tile[(tk * 64 + d4) ^ (tk & 7)];
      const float ex = cv.x - rv.x, ey = cv.y - rv.y, ez = cv.z - rv.z, ew = cv.w - rv.w;
      const float qsx = rv.x + ex, qsy = rv.y + ey, qsz = rv.z + ez, qsw = rv.w + ew;
      lsum += ex * ex + ey * ey + ez * ez + ew * ew;
      routp[j] = make_float4(rv.x - qsx, rv.y - qsy, rv.z - qsz, rv.w - qsw);
      float4 qo;
      if (q == 0) {
        qo = make_float4(qsx, qsy, qsz, qsw);
      } else {
        const float4 old = qoutp[j];
        qo = make_float4(old.x + qsx, old.y + qsy, old.z + qsz, old.w + qsw);
      }
      qoutp[j] = qo;
    }
  }
#pragma unroll
  for (int s = 32; s; s >>= 1) lsum += __shfl_xor(lsum, s);
  if (lane == 0) atomicAdd(&loss_acc[q], lsum);
}

// ---------------------------------------------------------------------------
__global__ void finalize_losses(const float* __restrict__ loss_acc,
                                float* __restrict__ loss_out) {
  if (threadIdx.x < Qq) loss_out[threadIdx.x] = loss_acc[threadIdx.x] * (1.0f / (float)(Mm * Dd));
}

extern "C" void kernel_launch(void* const* d_in, const int* in_sizes, int n_in,
                              void* d_out, int out_size, void* d_ws, size_t ws_size,
                              hipStream_t stream) {
  const float* x   = (const float*)d_in[0];   // [B,N,D]
  const float* cbs = (const float*)d_in[1];   // [Q,C,D]
  float* out      = (float*)d_out;
  float* qout     = out;                               // M*D
  float* idx_out  = out + (size_t)Mm * Dd;             // M*Q
  float* loss_out = idx_out + (size_t)Mm * Qq;         // Q

  char* w = (char*)d_ws;
  float* residual = (float*)w;                                  // 32 MB
  short* Bh       = (short*)(w + (size_t)33554432);             // 4 MB
  short* Bl       = (short*)(w + (size_t)37748736);             // 4 MB
  float* cnorm    = (float*)(w + (size_t)41943040);             // 32 KB
  float* loss_acc = (float*)(w + (size_t)41975808);             // 256 B

  prep_kernel<<<(Qq * Cc) / 4, NT, 0, stream>>>(cbs, cnorm, loss_acc);
  build_bfrag<<<Qq * 64, NT, 0, stream>>>(cbs, Bh, Bl);

  for (int q = 0; q < Qq; ++q) {
    const float* rin = (q == 0) ? x : residual;
    vq_stage<<<Mm / TOK, NT, 0, stream>>>(
        cbs + (size_t)q * Cc * Dd,
        (const short8*)Bh + (size_t)q * 32768,
        (const short8*)Bl + (size_t)q * 32768,
        cnorm + (size_t)q * Cc,
        rin, residual, qout, idx_out, loss_acc, q);
  }

  finalize_losses<<<1, 64, 0, stream>>>(loss_acc, loss_out);
}

// Round 6
// 1645.455 us; speedup vs baseline: 1.5195x; 1.1372x over previous
//
#include <hip/hip_runtime.h>

// Residual VQ via bf16-split MFMA distances + exact-fp32-chain margin rescue.
// x [B,N,D] fp32, codebooks [Q,C,D] fp32.
// d_out (flat fp32): qout [M*D], indices [M*Q] (as float), losses [Q]
typedef __attribute__((ext_vector_type(8))) short short8;
typedef __attribute__((ext_vector_type(4))) float f32x4;

constexpr int Bq = 8, Nn = 4096, Dd = 256, Qq = 8, Cc = 1024;
constexpr int Mm = Bq * Nn;        // 32768 tokens
constexpr int TOK = 64;            // tokens per block (4 waves x 16)
constexpr int NT = 256;
constexpr int LCAP = 16;           // rescue list capacity per token
constexpr float MARGIN = 0.5f;     // >= 2*max|mfma-approx - fp32-chain| on scores

__device__ inline unsigned short f2bf(float f) {          // fp32 -> bf16 RNE
  unsigned u = __float_as_uint(f);
  unsigned r = (u + 0x7FFFu + ((u >> 16) & 1u)) >> 16;
  return (unsigned short)r;
}
__device__ inline float bf2f(unsigned short h) { return __uint_as_float(((unsigned)h) << 16); }

// ---------------------------------------------------------------------------
// prep: cnorm[q*C+c] = sum_d cb[q][c][d]^2 ; zero loss accumulators
__global__ void prep_kernel(const float* __restrict__ cbs,
                            float* __restrict__ cnorm,
                            float* __restrict__ loss_acc) {
  const int wave = threadIdx.x >> 6;
  const int lane = threadIdx.x & 63;
  const int row  = blockIdx.x * 4 + wave;            // 0 .. Q*C-1
  const float4* r4 = reinterpret_cast<const float4*>(cbs + (size_t)row * Dd);
  const float4 v = r4[lane];
  float s = v.x * v.x + v.y * v.y + v.z * v.z + v.w * v.w;
#pragma unroll
  for (int off = 32; off; off >>= 1) s += __shfl_down(s, off);
  if (lane == 0) cnorm[row] = s;
  if (blockIdx.x == 0 && threadIdx.x < Qq) loss_acc[threadIdx.x] = 0.0f;
}

// ---------------------------------------------------------------------------
// Build frag-major bf16 hi/lo codebook: Bfrag[q][nt][ks][lane] (short8 each) =
// cb[q][ nt*16 + (lane&15) ][ ks*32 + (lane>>4)*8 + j ], j=0..7.
__global__ __launch_bounds__(NT)
void build_bfrag(const float* __restrict__ cbs,
                 short* __restrict__ Bh, short* __restrict__ Bl) {
  const int q    = blockIdx.x >> 6;      // grid = Q*64
  const int nt   = blockIdx.x & 63;
  const int lane = threadIdx.x & 63;
  const int ks0  = threadIdx.x >> 6;     // 0..3
#pragma unroll
  for (int h = 0; h < 2; ++h) {
    const int ks = ks0 + h * 4;
    const int c  = nt * 16 + (lane & 15);
    const int k  = ks * 32 + (lane >> 4) * 8;
    const float* src = cbs + ((size_t)(q * Cc + c)) * Dd + k;
    short8 hi, lo;
#pragma unroll
    for (int j = 0; j < 8; ++j) {
      const float f = src[j];
      const unsigned short hb = f2bf(f);
      hi[j] = (short)hb;
      lo[j] = (short)f2bf(f - bf2f(hb));
    }
    const size_t off = (((size_t)(q * 64 + nt) * 8 + ks) * 64 + lane);
    ((short8*)Bh)[off] = hi;
    ((short8*)Bl)[off] = lo;
  }
}

// ---------------------------------------------------------------------------
// exact fp32-chain score (bitwise-identical to the validated rounds-1..5 chain)
__device__ float exact_score(const float4* tile, int t, int sw,
                             const float* cb, const float* cnorm, int cand) {
  const float4* cv = reinterpret_cast<const float4*>(cb + (size_t)cand * Dd);
  float a = 0.0f;
#pragma unroll 1
  for (int d4 = 0; d4 < 64; ++d4) {
    const float4 rv = tile[(t * 64 + d4) ^ sw];
    const float4 c4 = cv[d4];
    a += rv.x * c4.x; a += rv.y * c4.y; a += rv.z * c4.z; a += rv.w * c4.w;
  }
  return cnorm[cand] - 2.0f * a;
}

// ---------------------------------------------------------------------------
// one VQ stage: 2-term bf16-split MFMA scores + margin collection -> rescue
// grid: Mm/TOK = 512 blocks x 256 threads (wave w owns tokens w*16..+16)
__global__ __launch_bounds__(NT, 2)
void vq_stage(const float* __restrict__ cb,      // [C][D] fp32 this stage
              const short8* __restrict__ bh,     // frag-major bf16 hi, this stage
              const short8* __restrict__ bl,     // frag-major bf16 lo
              const float* __restrict__ cnorm,   // [C] this stage
              const float* __restrict__ rin,     // [M][D] residual in
              float* __restrict__ rout,          // [M][D] residual out
              float* __restrict__ qout,          // [M][D] accumulated quantized
              float* __restrict__ idx_out,       // [M][Q] indices as float
              float* __restrict__ loss_acc,      // [Q]
              int q) {
  __shared__ float4 tile[TOK * 64];              // 64 KB fp32 residual, idx ^ (tok&7) swizzle
  __shared__ int cnt[TOK];
  __shared__ int list[TOK][LCAP];
  __shared__ int win[TOK];

  const int tid  = threadIdx.x;
  const int lane = tid & 63;
  const int wv   = tid >> 6;
  const int tok0 = blockIdx.x * TOK;

  // ---- phase A: stage fp32 residual tile (coalesced, XOR-swizzled rows)
  {
    const float4* src = reinterpret_cast<const float4*>(rin + (size_t)tok0 * Dd);
#pragma unroll
    for (int k = 0; k < 16; ++k) {
      const int j = tid + k * NT;
      const int tk = j >> 6, d4 = j & 63;
      tile[(tk * 64 + d4) ^ (tk & 7)] = src[j];
    }
  }
  if (tid < TOK) cnt[tid] = 0;
  __syncthreads();

  // ---- phase A2: per-lane A-fragments (bf16 hi only; lo_r term dropped —
  // score error sigma ~0.05 << MARGIN, rescue is exact anyway)
  short8 ah[8];
  {
    const int tk = wv * 16 + (lane & 15);
    const int sw = tk & 7;
#pragma unroll
    for (int ks = 0; ks < 8; ++ks) {
      const int d4 = ks * 8 + (lane >> 4) * 2;
      const float4 f0 = tile[(tk * 64 + d4) ^ sw];
      const float4 f1 = tile[(tk * 64 + d4 + 1) ^ sw];
      const float v[8] = {f0.x, f0.y, f0.z, f0.w, f1.x, f1.y, f1.z, f1.w};
#pragma unroll
      for (int j = 0; j < 8; ++j) ah[ks][j] = (short)f2bf(v[j]);
    }
  }

  // ---- phase B: 16 groups of 4 N-tiles; 8 indep MFMA chains + dbuf prefetch
  float runm[4] = {3.4e38f, 3.4e38f, 3.4e38f, 3.4e38f};
  const int col = lane & 15;
  const int g   = lane >> 4;                     // token rows g*4 .. g*4+3
#pragma unroll 1
  for (int np = 0; np < 16; ++np) {
    const int nt0 = np * 4;
    const short8* ph = bh + (size_t)nt0 * 512 + lane;
    const short8* pl = bl + (size_t)nt0 * 512 + lane;
    float cn[4];
#pragma unroll
    for (int j = 0; j < 4; ++j) cn[j] = cnorm[(nt0 + j) * 16 + col];

    f32x4 acch[4], accl[4];
#pragma unroll
    for (int j = 0; j < 4; ++j) { acch[j] = (f32x4){0.f,0.f,0.f,0.f}; accl[j] = (f32x4){0.f,0.f,0.f,0.f}; }

    short8 curh[4], curl[4], nxh[4], nxl[4];
#pragma unroll
    for (int j = 0; j < 4; ++j) { curh[j] = ph[j * 512]; curl[j] = pl[j * 512]; }
#pragma unroll
    for (int ks = 0; ks < 8; ++ks) {
      if (ks < 7) {
#pragma unroll
        for (int j = 0; j < 4; ++j) {
          nxh[j] = ph[j * 512 + (ks + 1) * 64];
          nxl[j] = pl[j * 512 + (ks + 1) * 64];
        }
      }
#pragma unroll
      for (int j = 0; j < 4; ++j) {
        acch[j] = __builtin_amdgcn_mfma_f32_16x16x32_bf16(ah[ks], curh[j], acch[j], 0, 0, 0);
        accl[j] = __builtin_amdgcn_mfma_f32_16x16x32_bf16(ah[ks], curl[j], accl[j], 0, 0, 0);
      }
#pragma unroll
      for (int j = 0; j < 4; ++j) { curh[j] = nxh[j]; curl[j] = nxl[j]; }
    }

    // bookkeeping: 16 independent shfl chains (4 tiles x 4 rows) interleaved
    float s[4][4], v[4][4];
#pragma unroll
    for (int j = 0; j < 4; ++j)
#pragma unroll
      for (int r = 0; r < 4; ++r) { s[j][r] = cn[j] - 2.0f * (acch[j][r] + accl[j][r]); v[j][r] = s[j][r]; }
#pragma unroll
    for (int m = 1; m < 16; m <<= 1)
#pragma unroll
      for (int j = 0; j < 4; ++j)
#pragma unroll
        for (int r = 0; r < 4; ++r) {
          const float o = __shfl_xor(v[j][r], m);
          v[j][r] = o < v[j][r] ? o : v[j][r];
        }
    // sequential prefix-min + margin collection (ascending tile order preserved)
#pragma unroll
    for (int j = 0; j < 4; ++j) {
#pragma unroll
      for (int r = 0; r < 4; ++r) {
        const float nr = v[j][r] < runm[r] ? v[j][r] : runm[r];
        runm[r] = nr;
        if (s[j][r] <= nr + MARGIN) {
          const int t = wv * 16 + g * 4 + r;
          const int pos = atomicAdd(&cnt[t], 1);
          if (pos < LCAP) list[t][pos] = (nt0 + j) * 16 + col;
        }
      }
    }
  }
  __syncthreads();

  // ---- phase C: rescue (one thread per token). cnt==1 -> proven exact winner.
  if (tid < TOK) {
    const int t = tid;
    const int sw = t & 7;
    const int c_ = cnt[t];
    int wdx;
    if (c_ == 1) {
      wdx = list[t][0];
    } else if (c_ <= LCAP) {
      float best = 3.4e38f; wdx = 1 << 30;
      for (int it = 0; it < c_; ++it) {
        const int cand = list[t][it];
        const float sc = exact_score(tile, t, sw, cb, cnorm, cand);
        if (sc < best || (sc == best && cand < wdx)) { best = sc; wdx = cand; }
      }
    } else {            // overflow safety net: full exact scan (never expected)
      float best = 3.4e38f; wdx = 1 << 30;
      for (int cand = 0; cand < Cc; ++cand) {
        const float sc = exact_score(tile, t, sw, cb, cnorm, cand);
        if (sc < best) { best = sc; wdx = cand; }
      }
    }
    win[t] = wdx;
    idx_out[(size_t)(tok0 + t) * Qq + q] = (float)wdx;
  }
  __syncthreads();

  // ---- phase D: epilogue (bitwise-validated elementwise sequence)
  //   e = q - r; q_st = r + e; r_new = r - q_st; qout += q_st; loss += e^2
  float lsum = 0.0f;
  {
    const float4* cb4 = reinterpret_cast<const float4*>(cb);
    float4* routp = reinterpret_cast<float4*>(rout + (size_t)tok0 * Dd);
    float4* qoutp = reinterpret_cast<float4*>(qout + (size_t)tok0 * Dd);
#pragma unroll
    for (int k = 0; k < 16; ++k) {
      const int j = tid + k * NT;
      const int tk = j >> 6, d4 = j & 63;
      const int widx = win[tk];
      const float4 cv = cb4[(size_t)widx * 64 + d4];
      const float4 rv = tile[(tk * 64 + d4) ^ (tk & 7)];
      const float ex = cv.x - rv.x, ey = cv.y - rv.y, ez = cv.z - rv.z, ew = cv.w - rv.w;
      const float qsx = rv.x + ex, qsy = rv.y + ey, qsz = rv.z + ez, qsw = rv.w + ew;
      lsum += ex * ex + ey * ey + ez * ez + ew * ew;
      routp[j] = make_float4(rv.x - qsx, rv.y - qsy, rv.z - qsz, rv.w - qsw);
      float4 qo;
      if (q == 0) {
        qo = make_float4(qsx, qsy, qsz, qsw);
      } else {
        const float4 old = qoutp[j];
        qo = make_float4(old.x + qsx, old.y + qsy, old.z + qsz, old.w + qsw);
      }
      qoutp[j] = qo;
    }
  }
#pragma unroll
  for (int s = 32; s; s >>= 1) lsum += __shfl_xor(lsum, s);
  if (lane == 0) atomicAdd(&loss_acc[q], lsum);
}

// ---------------------------------------------------------------------------
__global__ void finalize_losses(const float* __restrict__ loss_acc,
                                float* __restrict__ loss_out) {
  if (threadIdx.x < Qq) loss_out[threadIdx.x] = loss_acc[threadIdx.x] * (1.0f / (float)(Mm * Dd));
}

extern "C" void kernel_launch(void* const* d_in, const int* in_sizes, int n_in,
                              void* d_out, int out_size, void* d_ws, size_t ws_size,
                              hipStream_t stream) {
  const float* x   = (const float*)d_in[0];   // [B,N,D]
  const float* cbs = (const float*)d_in[1];   // [Q,C,D]
  float* out      = (float*)d_out;
  float* qout     = out;                               // M*D
  float* idx_out  = out + (size_t)Mm * Dd;             // M*Q
  float* loss_out = idx_out + (size_t)Mm * Qq;         // Q

  char* w = (char*)d_ws;
  float* residual = (float*)w;                                  // 32 MB
  short* Bh       = (short*)(w + (size_t)33554432);             // 4 MB
  short* Bl       = (short*)(w + (size_t)37748736);             // 4 MB
  float* cnorm    = (float*)(w + (size_t)41943040);             // 32 KB
  float* loss_acc = (float*)(w + (size_t)41975808);             // 256 B

  prep_kernel<<<(Qq * Cc) / 4, NT, 0, stream>>>(cbs, cnorm, loss_acc);
  build_bfrag<<<Qq * 64, NT, 0, stream>>>(cbs, Bh, Bl);

  for (int q = 0; q < Qq; ++q) {
    const float* rin = (q == 0) ? x : residual;
    vq_stage<<<Mm / TOK, NT, 0, stream>>>(
        cbs + (size_t)q * Cc * Dd,
        (const short8*)Bh + (size_t)q * 32768,
        (const short8*)Bl + (size_t)q * 32768,
        cnorm + (size_t)q * Cc,
        rin, residual, qout, idx_out, loss_acc, q);
  }

  finalize_losses<<<1, 64, 0, stream>>>(loss_acc, loss_out);
}